// Round 4
// baseline (682.815 us; speedup 1.0000x reference)
//
#include <hip/hip_runtime.h>
#include <hip/hip_bf16.h>

// Problem constants (from setup_inputs)
#define BATCH 16
#define D_IN  1024
#define T_LEN 2048
#define K_CB  4096
#define D_CB  256

// d_out layout (float32, concatenated in return order)
#define ZI_OFF 0
#define ZQ_OFF (BATCH * D_CB * T_LEN)                 // 8388608
#define ZO_OFF (ZQ_OFF + BATCH * D_CB * T_LEN)       // 16777216
#define IDX_OFF (ZO_OFF + BATCH * D_IN * T_LEN)      // 50331648

typedef _Float16 half8 __attribute__((ext_vector_type(8)));
typedef _Float16 h4_t  __attribute__((ext_vector_type(4)));
typedef float floatx4 __attribute__((ext_vector_type(4)));

// ---------------- block reduce (256 threads) ----------------
__device__ __forceinline__ float block_sum256(float v) {
    __shared__ float sred[4];
    #pragma unroll
    for (int off = 32; off > 0; off >>= 1) v += __shfl_down(v, off, 64);
    if ((threadIdx.x & 63) == 0) sred[threadIdx.x >> 6] = v;
    __syncthreads();
    float r = sred[0] + sred[1] + sred[2] + sred[3];
    __syncthreads();
    return r;
}

// ---------------- weight norm -> packed f16-split fragment layout ----------------
// W[row] = g[row] * v[row] / ||v[row]||, emitted as
//   wp[((otile*(N/32) + ks)*2 + sp)*512 + (quad*16 + lo4)*8 + j]
// where otile=row>>4, lo4=row&15, ks=c>>5, quad=(c>>3)&3, j=c&7.
// A wave's B-fragment for (otile,ks,sp) is 64 lanes x 16B = 1 KB contiguous.
__global__ __launch_bounds__(256) void wn_rows(const float* __restrict__ v,
                                               const float* __restrict__ g,
                                               _Float16* __restrict__ wp, int N) {
    int row = blockIdx.x;
    const float* src = v + (size_t)row * N;
    float ss = 0.f;
    for (int c = threadIdx.x; c < N; c += 256) { float x = src[c]; ss += x * x; }
    ss = block_sum256(ss);
    float scale = g[row] * __frsqrt_rn(ss);
    int otile = row >> 4, lo4o = row & 15;
    int nks = N >> 5;
    for (int c = threadIdx.x; c < N; c += 256) {
        float val = src[c] * scale;
        _Float16 h1 = (_Float16)val;
        _Float16 h2 = (_Float16)(val - (float)h1);
        int ks = c >> 5, quad = (c >> 3) & 3, j = c & 7;
        size_t base = ((size_t)(otile * nks + ks) * 2) * 512 + (quad * 16 + lo4o) * 8 + j;
        wp[base] = h1;           // sp = 0
        wp[base + 512] = h2;     // sp = 1
    }
}

// ---------------- codebook: normalize + 2-way fp16 split, packed fragment order ----
__global__ __launch_bounds__(256) void cb_prep(const float* __restrict__ cb,
                                               _Float16* __restrict__ cbt) {
    int row = blockIdx.x;            // cw: 0..4095
    int c = threadIdx.x;             // k:  0..255
    float x = cb[(size_t)row * D_CB + c];
    float ss = block_sum256(x * x);
    float scale = 1.0f / fmaxf(sqrtf(ss), 1e-12f);
    float v = x * scale;
    _Float16 h1 = (_Float16)v;
    _Float16 h2 = (_Float16)(v - (float)h1);
    int tt = row >> 4, lo4 = row & 15;
    int ks = c >> 5, quad = (c >> 3) & 3, j = c & 7;
    size_t base = ((size_t)(tt * 16 + ks * 2)) * 512 + (quad * 16 + lo4) * 8 + j;
    cbt[base] = h1;            // sp = 0
    cbt[base + 512] = h2;      // sp = 1
}

// ---------------- projection via f16-split MFMA, B direct from packed global ----------------
// Out[b,o,t] = sum_c W[o,c]*Z[b,c,t] + bias[o]
// 128 frames x 128 o per block, 4 waves (2 frame-halves x 2 o-halves), 64x64/wave.
// A (z) staged+split through LDS; B (W) loaded as packed fragments global->VGPR.
template <int KDIM, int M>
__global__ __launch_bounds__(256, 2) void proj_mfma(const _Float16* __restrict__ wp,
                                                    const float* __restrict__ bias,
                                                    const float* __restrict__ Z,
                                                    float* __restrict__ Out) {
    __shared__ _Float16 A_s[2][128][40];   // [split][frame][k], pad 40

    const int tid  = threadIdx.x;
    const int wv   = tid >> 6;
    const int lane = tid & 63;
    const int lo4  = lane & 15, quad = lane >> 4;
    const int wm   = wv & 1,  wn  = wv >> 1;

    const int f0 = blockIdx.x * 128;
    const int b  = f0 >> 11;
    const int t0 = f0 & (T_LEN - 1);
    const int o0 = blockIdx.y * 128;
    const float* __restrict__ Zb = Z + (size_t)b * KDIM * T_LEN;
    const _Float16* __restrict__ wp_lane = wp + lane * 8;
    const int otile_base = (o0 >> 4) + wn * 4;

    const int a_g  = tid >> 5;             // k-quad group 0..7
    const int a_tl = tid & 31;             // frame lane

    float pa[4][4];

    floatx4 acc[4][4];
    #pragma unroll
    for (int i = 0; i < 4; i++)
        #pragma unroll
        for (int j = 0; j < 4; j++) acc[i][j] = (floatx4){0.f, 0.f, 0.f, 0.f};

    // prefetch kk = 0 A-tile
    #pragma unroll
    for (int p = 0; p < 4; p++)
        #pragma unroll
        for (int j = 0; j < 4; j++)
            pa[p][j] = Zb[(size_t)(a_g * 4 + j) * T_LEN + t0 + p * 32 + a_tl];

    for (int kk = 0; kk < KDIM; kk += 32) {
        // ---- stage prefetched A tile (split + transpose) ----
        #pragma unroll
        for (int p = 0; p < 4; p++) {
            int f = p * 32 + a_tl;
            h4_t h1, h2;
            #pragma unroll
            for (int j = 0; j < 4; j++) {
                float v = pa[p][j];
                _Float16 x = (_Float16)v;
                h1[j] = x;
                h2[j] = (_Float16)(v - (float)x);
            }
            *(h4_t*)&A_s[0][f][a_g * 4] = h1;
            *(h4_t*)&A_s[1][f][a_g * 4] = h2;
        }
        __syncthreads();

        // prefetch next A tile
        if (kk + 32 < KDIM) {
            #pragma unroll
            for (int p = 0; p < 4; p++)
                #pragma unroll
                for (int j = 0; j < 4; j++)
                    pa[p][j] = Zb[(size_t)(kk + 32 + a_g * 4 + j) * T_LEN + t0 + p * 32 + a_tl];
        }

        // B fragments straight from packed global (L1/L2-hot, 1 KB coalesced each)
        const int kk32 = kk >> 5;
        half8 b1[4], b2[4];
        #pragma unroll
        for (int ni = 0; ni < 4; ni++) {
            const _Float16* src = wp_lane + ((size_t)((otile_base + ni) * (KDIM / 32) + kk32) * 2) * 512;
            b1[ni] = *(const half8*)(src);
            b2[ni] = *(const half8*)(src + 512);
        }

        half8 a1[4], a2[4];
        #pragma unroll
        for (int mi = 0; mi < 4; mi++) {
            a1[mi] = *(const half8*)&A_s[0][wm * 64 + mi * 16 + lo4][quad * 8];
            a2[mi] = *(const half8*)&A_s[1][wm * 64 + mi * 16 + lo4][quad * 8];
        }
        #pragma unroll
        for (int mi = 0; mi < 4; mi++)
            #pragma unroll
            for (int ni = 0; ni < 4; ni++) {
                acc[mi][ni] = __builtin_amdgcn_mfma_f32_16x16x32_f16(a1[mi], b1[ni], acc[mi][ni], 0, 0, 0);
                acc[mi][ni] = __builtin_amdgcn_mfma_f32_16x16x32_f16(a1[mi], b2[ni], acc[mi][ni], 0, 0, 0);
                acc[mi][ni] = __builtin_amdgcn_mfma_f32_16x16x32_f16(a2[mi], b1[ni], acc[mi][ni], 0, 0, 0);
            }
        __syncthreads();
    }

    // epilogue: C layout col(o)=lane&15, row(frame)=quad*4+reg -> float4 along t
    #pragma unroll
    for (int ni = 0; ni < 4; ni++) {
        int o = o0 + wn * 64 + ni * 16 + lo4;
        float bv = bias[o];
        #pragma unroll
        for (int mi = 0; mi < 4; mi++) {
            int t = t0 + wm * 64 + mi * 16 + quad * 4;
            floatx4 r = acc[mi][ni];
            float4 st = make_float4(r[0] + bv, r[1] + bv, r[2] + bv, r[3] + bv);
            *(float4*)&Out[((size_t)b * M + o) * T_LEN + t] = st;
        }
    }
}

// ---------------- VQ v3: 128 frames/block, 4 waves convoy over shared codebook tiles ----------------
// Each wave owns 32 frames (A in registers); ALL waves scan tiles 0..255 in lockstep
// (raw s_barrier per tile) so B loads dedup in L1/L2. 3 acc chains cut MFMA dependency depth.
__global__ __launch_bounds__(256, 2) void vq_mfma(const float* __restrict__ z_i,
                                                  const _Float16* __restrict__ cbt,
                                                  const float* __restrict__ cb,
                                                  float* __restrict__ z_q,
                                                  float* __restrict__ idx_out) {
    __shared__ _Float16 e_s[2][32][264];   // staging for one 32-frame group
    __shared__ int idx_s[128];

    const int tid  = threadIdx.x;
    const int wv   = tid >> 6;
    const int lane = tid & 63;
    const int lo4  = lane & 15, quad = lane >> 4;
    const int f0 = blockIdx.x * 128;
    const int b  = f0 >> 11;               // f0 / T_LEN
    const int t0 = f0 & (T_LEN - 1);

    // ---- stage 128 frames in 4 phases; wave p hoists phase p's fragments ----
    half8 a1[2][8], a2[2][8];
    for (int ph = 0; ph < 4; ph++) {
        for (int i = tid; i < 32 * 256; i += 256) {
            int k = i >> 5, t = i & 31;
            float v = z_i[((size_t)(b * D_CB + k)) * T_LEN + t0 + ph * 32 + t];
            _Float16 h1 = (_Float16)v;
            _Float16 h2 = (_Float16)(v - (float)h1);
            e_s[0][t][k] = h1;
            e_s[1][t][k] = h2;
        }
        __syncthreads();
        if (wv == ph) {
            #pragma unroll
            for (int m = 0; m < 2; m++)
                #pragma unroll
                for (int ks = 0; ks < 8; ks++) {
                    a1[m][ks] = *(const half8*)&e_s[0][m * 16 + lo4][ks * 32 + quad * 8];
                    a2[m][ks] = *(const half8*)&e_s[1][m * 16 + lo4][ks * 32 + quad * 8];
                }
        }
        __syncthreads();
    }

    float best_v[2][4];
    int   best_i[2][4];
    #pragma unroll
    for (int m = 0; m < 2; m++)
        #pragma unroll
        for (int r = 0; r < 4; r++) { best_v[m][r] = -3.4e38f; best_i[m][r] = 0; }

    const _Float16* cb_lane = cbt + lane * 8;

    half8 b1[8], b2[8];
    #pragma unroll
    for (int ks = 0; ks < 8; ks++) {
        b1[ks] = *(const half8*)(cb_lane + ks * 1024);
        b2[ks] = *(const half8*)(cb_lane + ks * 1024 + 512);
    }

    for (int tt = 0; tt < 256; tt++) {
        __builtin_amdgcn_s_barrier();      // keep the 4-wave convoy aligned for L1 reuse
        floatx4 accA[2], accB[2], accC[2];
        #pragma unroll
        for (int m = 0; m < 2; m++) {
            accA[m] = (floatx4){0.f,0.f,0.f,0.f};
            accB[m] = (floatx4){0.f,0.f,0.f,0.f};
            accC[m] = (floatx4){0.f,0.f,0.f,0.f};
        }

        const int ttn = (tt + 1 < 256) ? tt + 1 : 0;   // clamped prefetch target
        const _Float16* nb = cb_lane + (size_t)ttn * 8192;

        #pragma unroll
        for (int ks = 0; ks < 8; ks++) {
            half8 cb1 = b1[ks], cb2 = b2[ks];
            accA[0] = __builtin_amdgcn_mfma_f32_16x16x32_f16(a1[0][ks], cb1, accA[0], 0, 0, 0);
            accB[0] = __builtin_amdgcn_mfma_f32_16x16x32_f16(a1[0][ks], cb2, accB[0], 0, 0, 0);
            accC[0] = __builtin_amdgcn_mfma_f32_16x16x32_f16(a2[0][ks], cb1, accC[0], 0, 0, 0);
            accA[1] = __builtin_amdgcn_mfma_f32_16x16x32_f16(a1[1][ks], cb1, accA[1], 0, 0, 0);
            accB[1] = __builtin_amdgcn_mfma_f32_16x16x32_f16(a1[1][ks], cb2, accB[1], 0, 0, 0);
            accC[1] = __builtin_amdgcn_mfma_f32_16x16x32_f16(a2[1][ks], cb1, accC[1], 0, 0, 0);
            // reload this k-step's B for the next tile (slack ~ one full tile of MFMAs)
            b1[ks] = *(const half8*)(nb + ks * 1024);
            b2[ks] = *(const half8*)(nb + ks * 1024 + 512);
        }

        // fold: C/D layout col(cw)=lane&15, row(frame)=quad*4+reg
        const int cwi = tt * 16 + lo4;
        #pragma unroll
        for (int m = 0; m < 2; m++)
            #pragma unroll
            for (int r = 0; r < 4; r++) {
                float v = accA[m][r] + accB[m][r] + accC[m][r];
                if (v > best_v[m][r] || (v == best_v[m][r] && cwi < best_i[m][r])) {
                    best_v[m][r] = v; best_i[m][r] = cwi;
                }
            }
    }

    // reduce across the 16 column-lanes within each quad; frames are wave-disjoint
    #pragma unroll
    for (int m = 0; m < 2; m++)
        #pragma unroll
        for (int r = 0; r < 4; r++) {
            float bv = best_v[m][r]; int bi = best_i[m][r];
            #pragma unroll
            for (int off = 8; off > 0; off >>= 1) {
                float ov = __shfl_down(bv, off, 16);
                int   oi = __shfl_down(bi, off, 16);
                if (ov > bv || (ov == bv && oi < bi)) { bv = ov; bi = oi; }
            }
            if (lo4 == 0) {
                int fr = wv * 32 + m * 16 + quad * 4 + r;
                idx_s[fr] = bi;
                idx_out[f0 + fr] = (float)bi;
            }
        }
    __syncthreads();

    // z_q[b,c,t0+f] = codebook[idx_f][c]
    for (int i = tid; i < 128 * 256; i += 256) {
        int k = i >> 7, t = i & 127;
        z_q[((size_t)(b * D_CB + k)) * T_LEN + t0 + t] = cb[(size_t)idx_s[t] * D_CB + k];
    }
}

extern "C" void kernel_launch(void* const* d_in, const int* in_sizes, int n_in,
                              void* d_out, int out_size, void* d_ws, size_t ws_size,
                              hipStream_t stream) {
    const float* z     = (const float*)d_in[0];
    const float* in_v  = (const float*)d_in[1];
    const float* in_g  = (const float*)d_in[2];
    const float* in_b  = (const float*)d_in[3];
    const float* out_v = (const float*)d_in[4];
    const float* out_g = (const float*)d_in[5];
    const float* out_b = (const float*)d_in[6];
    const float* cb    = (const float*)d_in[7];

    float* ws = (float*)d_ws;
    _Float16* wp_in  = (_Float16*)ws;                 // packed split W_in  (1 MB)
    _Float16* wp_out = (_Float16*)(ws + 262144);      // packed split W_out (1 MB)
    _Float16* cbt    = (_Float16*)(ws + 524288);      // packed split codebook (4 MB)

    float* out  = (float*)d_out;
    float* z_i  = out + ZI_OFF;
    float* z_q  = out + ZQ_OFF;
    float* z_o  = out + ZO_OFF;
    float* idxf = out + IDX_OFF;

    // weight-norm (packed split) + codebook normalize/split/pack
    wn_rows<<<D_CB, 256, 0, stream>>>(in_v, in_g, wp_in, D_IN);
    wn_rows<<<D_IN, 256, 0, stream>>>(out_v, out_g, wp_out, D_CB);
    cb_prep<<<K_CB, 256, 0, stream>>>(cb, cbt);

    // z_i = W_in @ z + in_b
    proj_mfma<D_IN, D_CB><<<dim3((BATCH * T_LEN) / 128, D_CB / 128), 256, 0, stream>>>(wp_in, in_b, z, z_i);

    // nearest codeword + z_q + indices
    vq_mfma<<<(BATCH * T_LEN) / 128, 256, 0, stream>>>(z_i, cbt, cb, z_q, idxf);

    // z_o = W_out @ z_q + out_b
    proj_mfma<D_CB, D_IN><<<dim3((BATCH * T_LEN) / 128, D_IN / 128), 256, 0, stream>>>(wp_out, out_b, z_q, z_o);
}